// Round 11
// baseline (508.533 us; speedup 1.0000x reference)
//
#include <hip/hip_runtime.h>
#include <hip/hip_bf16.h>
#include <hip/hip_cooperative_groups.h>

namespace cg = cooperative_groups;

// Problem constants
constexpr int B_  = 2;
constexpr int L_  = 1024;
constexpr int DIN = 1024;
constexpr int DM  = 2048;
constexpr int DS  = 16;
constexpr int DR  = 128;
constexpr int KC  = 4;       // conv kernel size
constexpr int M_  = B_ * L_; // 2048 rows
constexpr int NP2 = 256;     // packed projection width (16+16+128 padded to 256)
constexpr int KSLICES = 8;   // split-K for proj GEMM (K slice = 256)
constexpr int KSL = DM / KSLICES;     // 256

// Chunked scan parameters
constexpr int NC = 32;               // number of chunks
constexpr int CL = L_ / NC;          // chunk length (32)
constexpr int S_ = B_ * DM * DS;     // 65536 scan states

typedef __bf16 bf16x8 __attribute__((ext_vector_type(8)));
typedef float  f32x4  __attribute__((ext_vector_type(4)));

// ---------------------------------------------------------------------------
// async global->LDS 16B copy (global_load_lds_dwordx4).
// ---------------------------------------------------------------------------
__device__ __forceinline__ void gload_lds16(const void* g, void* l) {
    __builtin_amdgcn_global_load_lds(
        (const __attribute__((address_space(1))) void*)g,
        (__attribute__((address_space(3))) void*)l, 16, 0, 0);
}

// ---------------------------------------------------------------------------
// Fused operand prep (one launch): convert + 4 transposes + proj pack +
// conv-weight transpose + zero the P accumulator (for proj atomics).
// ---------------------------------------------------------------------------
__device__ __forceinline__ void transpose_block(const float* __restrict__ in,
                                                __bf16* __restrict__ out,
                                                int R, int C, int bx, int by, int t) {
    __shared__ float tile[32][33];
    int tx = t & 31, ty = t >> 5;   // (32, 8)
    #pragma unroll
    for (int j = 0; j < 32; j += 8)
        tile[ty + j][tx] = in[(size_t)(by * 32 + ty + j) * C + (bx * 32 + tx)];
    __syncthreads();
    #pragma unroll
    for (int j = 0; j < 32; j += 8)
        out[(size_t)(bx * 32 + ty + j) * R + (by * 32 + tx)] = (__bf16)tile[tx][ty + j];
}

__global__ void prep_all(const float* __restrict__ x_in, const float* __restrict__ W_in,
                         const float* __restrict__ W_res, const float* __restrict__ W_out,
                         const float* __restrict__ dt_w,
                         const float* __restrict__ W_B, const float* __restrict__ W_C,
                         const float* __restrict__ W_dt, const float* __restrict__ conv_w,
                         __bf16* __restrict__ xinB, __bf16* __restrict__ WinT,
                         __bf16* __restrict__ WresT, __bf16* __restrict__ WoutT,
                         __bf16* __restrict__ dtwT, __bf16* __restrict__ projW,
                         float* __restrict__ cwT, float* __restrict__ P) {
    int blk = blockIdx.x, t = threadIdx.x;
    if (blk < 8192) {
        int i = blk * 256 + t;
        xinB[i] = (__bf16)x_in[i];
    } else if (blk < 10240) {
        int b = blk - 8192;                       // grid (64, 32)
        transpose_block(W_in, WinT, DIN, DM, b % 64, b / 64, t);
    } else if (blk < 12288) {
        int b = blk - 10240;
        transpose_block(W_res, WresT, DIN, DM, b % 64, b / 64, t);
    } else if (blk < 14336) {
        int b = blk - 12288;                      // grid (32, 64)
        transpose_block(W_out, WoutT, DM, DIN, b % 32, b / 32, t);
    } else if (blk < 14592) {
        int b = blk - 14336;                      // grid (64, 4)
        transpose_block(dt_w, dtwT, DR, DM, b % 64, b / 64, t);
    } else if (blk < 16640) {
        int i = (blk - 14592) * 256 + t;          // 0 .. NP2*DM
        int k = i % DM;
        int n = i / DM;
        float v = 0.f;
        if (n < 16)        v = W_B[(size_t)k * DS + n];
        else if (n < 32)   v = W_C[(size_t)k * DS + (n - 16)];
        else if (n < 160)  v = W_dt[(size_t)k * DR + (n - 32)];
        projW[i] = (__bf16)v;
    } else if (blk < 16672) {
        int j = (blk - 16640) * 256 + t;          // 0 .. KC*DM
        int tap = j / DM, d = j % DM;
        cwT[j] = conv_w[d * KC + tap];
    } else {
        int i = (blk - 16672) * 256 + t;          // 0 .. M_*NP2/4
        ((f32x4*)P)[i] = f32x4{0.f, 0.f, 0.f, 0.f};
    }
}

// ---------------------------------------------------------------------------
// m97-style MFMA GEMM: 128x128 block tile, BK=32, LDS-staged via
// global_load_lds width=16, XOR-swizzled slots. 4 waves, each 64x64.
// EPI: 0 = plain f32 partial store (stride N, z-slice offset);
//      1 = +bias[col], softplus -> bf16 Cb (stride N);
//      2 = dual-output bf16: col<DM -> (bf16*)Cf (x), else -> Cb (res), stride DM;
//      3 = split-K accumulate: atomicAdd into Cf (stride N), only col<160.
// ---------------------------------------------------------------------------
template<int EPI>
__global__ void gemm_tile128(const __bf16* __restrict__ A, const __bf16* __restrict__ BT,
                             float* __restrict__ Cf, __bf16* __restrict__ Cb,
                             const float* __restrict__ bias, int M, int N, int K,
                             int lda, int ldb) {
    __shared__ __bf16 sA[128 * 32];
    __shared__ __bf16 sB[128 * 32];
    int t = threadIdx.x;
    int lane = t & 63, w = t >> 6;
    int wm = w >> 1, wn = w & 1;
    int m0 = blockIdx.y * 128, n0 = blockIdx.x * 128;
    int kbase = blockIdx.z * K;
    int q = lane >> 4, rr = lane & 15;

    f32x4 acc[4][4] = {};

    int srow = t >> 2;          // 0..63 (staging row, +64 on round 1)
    int slot = t & 3;           // physical 8-elem slot within the 32-wide k

    for (int kt = 0; kt < K; kt += 32) {
        __syncthreads();
        #pragma unroll
        for (int rnd = 0; rnd < 2; rnd++) {
            int row = srow + rnd * 64;
            int gkb = slot ^ ((row >> 1) & 3);          // logical k-block fetched into this slot
            const __bf16* ga = A  + (size_t)(m0 + row) * lda + kbase + kt + gkb * 8;
            const __bf16* gb = BT + (size_t)(n0 + row) * ldb + kbase + kt + gkb * 8;
            __bf16* la = sA + rnd * 2048 + w * 512;     // wave-uniform base
            __bf16* lb = sB + rnd * 2048 + w * 512;
            gload_lds16(ga, la);
            gload_lds16(gb, lb);
        }
        __syncthreads();

        bf16x8 af[4], bfr[4];
        #pragma unroll
        for (int i = 0; i < 4; i++) {
            int rowA = wm * 64 + i * 16 + rr;
            af[i] = *(const bf16x8*)(sA + rowA * 32 + ((q ^ ((rowA >> 1) & 3)) * 8));
            int rowB = wn * 64 + i * 16 + rr;
            bfr[i] = *(const bf16x8*)(sB + rowB * 32 + ((q ^ ((rowB >> 1) & 3)) * 8));
        }
        #pragma unroll
        for (int i = 0; i < 4; i++)
            #pragma unroll
            for (int j = 0; j < 4; j++)
                acc[i][j] = __builtin_amdgcn_mfma_f32_16x16x32_bf16(af[i], bfr[j], acc[i][j], 0, 0, 0);
    }

    float* Cz = Cf + (size_t)blockIdx.z * M * N;
    #pragma unroll
    for (int i = 0; i < 4; i++) {
        #pragma unroll
        for (int j = 0; j < 4; j++) {
            int col = n0 + wn * 64 + j * 16 + rr;
            #pragma unroll
            for (int jj = 0; jj < 4; jj++) {
                int row = m0 + wm * 64 + i * 16 + q * 4 + jj;
                float v = acc[i][j][jj];
                if (EPI == 0) {
                    Cz[(size_t)row * N + col] = v;
                } else if (EPI == 1) {
                    float z = v + bias[col];
                    Cb[(size_t)row * N + col] = (__bf16)((z > 20.f) ? z : log1pf(__expf(z)));
                } else if (EPI == 2) {
                    if (col < DM) ((__bf16*)Cf)[(size_t)row * DM + col] = (__bf16)v;
                    else          Cb[(size_t)row * DM + (col - DM)] = (__bf16)v;
                } else {
                    if (col < 160) atomicAdd(&Cf[(size_t)row * N + col], v);
                }
            }
        }
    }
}

// ---------------------------------------------------------------------------
// delta GEMM: delta = softplus(dtmp @ dt_w + dt_b) -> bf16.
// A = dtmp is f32 in P cols [32,160); loaded direct from global (L2-hot, 1 MB)
// with in-register bf16 convert. B (dtwT) staged via LDS as usual. K = DR.
// Grid (DM/128, M/128), 4 waves x 64x64.
// ---------------------------------------------------------------------------
__global__ void gemm_delta(const float* __restrict__ P, const __bf16* __restrict__ BT,
                           const float* __restrict__ bias, __bf16* __restrict__ Cb,
                           int M, int N) {
    __shared__ __bf16 sB[128 * 32];
    int t = threadIdx.x;
    int lane = t & 63, w = t >> 6;
    int wm = w >> 1, wn = w & 1;
    int m0 = blockIdx.y * 128, n0 = blockIdx.x * 128;
    int q = lane >> 4, rr = lane & 15;

    f32x4 acc[4][4] = {};
    int srow = t >> 2;
    int slot = t & 3;

    for (int kt = 0; kt < DR; kt += 32) {
        __syncthreads();
        #pragma unroll
        for (int rnd = 0; rnd < 2; rnd++) {
            int row = srow + rnd * 64;
            int gkb = slot ^ ((row >> 1) & 3);
            const __bf16* gb = BT + (size_t)(n0 + row) * DR + kt + gkb * 8;
            __bf16* lb = sB + rnd * 2048 + w * 512;
            gload_lds16(gb, lb);
        }
        __syncthreads();

        bf16x8 af[4], bfr[4];
        #pragma unroll
        for (int i = 0; i < 4; i++) {
            int rowA = m0 + wm * 64 + i * 16 + rr;
            const f32x4* ap = (const f32x4*)(P + (size_t)rowA * NP2 + 32 + kt + q * 8);
            f32x4 a0 = ap[0], a1 = ap[1];
            bf16x8 av;
            #pragma unroll
            for (int c = 0; c < 4; c++) { av[c] = (__bf16)a0[c]; av[4 + c] = (__bf16)a1[c]; }
            af[i] = av;
            int rowB = wn * 64 + i * 16 + rr;
            bfr[i] = *(const bf16x8*)(sB + rowB * 32 + ((q ^ ((rowB >> 1) & 3)) * 8));
        }
        #pragma unroll
        for (int i = 0; i < 4; i++)
            #pragma unroll
            for (int j = 0; j < 4; j++)
                acc[i][j] = __builtin_amdgcn_mfma_f32_16x16x32_bf16(af[i], bfr[j], acc[i][j], 0, 0, 0);
    }

    #pragma unroll
    for (int i = 0; i < 4; i++) {
        #pragma unroll
        for (int j = 0; j < 4; j++) {
            int col = n0 + wn * 64 + j * 16 + rr;
            float bz = bias[col];
            #pragma unroll
            for (int jj = 0; jj < 4; jj++) {
                int row = m0 + wm * 64 + i * 16 + q * 4 + jj;
                float z = acc[i][j][jj] + bz;
                Cb[(size_t)row * N + col] = (__bf16)((z > 20.f) ? z : log1pf(__expf(z)));
            }
        }
    }
}

// ---------------------------------------------------------------------------
// Out GEMM: 128(M)x64(N) tile, 4 waves each 32x64, direct f32 store.
// ---------------------------------------------------------------------------
__global__ void gemm_out64(const __bf16* __restrict__ A, const __bf16* __restrict__ BT,
                           float* __restrict__ C, int M, int N, int K, int lda, int ldb) {
    __shared__ __bf16 sA[128 * 32];
    __shared__ __bf16 sB[64 * 32];
    int t = threadIdx.x;
    int lane = t & 63, w = t >> 6;
    int m0 = blockIdx.y * 128, n0 = blockIdx.x * 64;
    int q = lane >> 4, rr = lane & 15;

    f32x4 acc[2][4] = {};
    int srow = t >> 2;
    int slot = t & 3;

    for (int kt = 0; kt < K; kt += 32) {
        __syncthreads();
        #pragma unroll
        for (int rnd = 0; rnd < 2; rnd++) {
            int row = srow + rnd * 64;
            int gkb = slot ^ ((row >> 1) & 3);
            const __bf16* ga = A + (size_t)(m0 + row) * lda + kt + gkb * 8;
            __bf16* la = sA + rnd * 2048 + w * 512;
            gload_lds16(ga, la);
        }
        {
            int row = srow;
            int gkb = slot ^ ((row >> 1) & 3);
            const __bf16* gb = BT + (size_t)(n0 + row) * ldb + kt + gkb * 8;
            __bf16* lb = sB + w * 512;
            gload_lds16(gb, lb);
        }
        __syncthreads();

        bf16x8 af[2], bfr[4];
        #pragma unroll
        for (int i = 0; i < 2; i++) {
            int rowA = w * 32 + i * 16 + rr;
            af[i] = *(const bf16x8*)(sA + rowA * 32 + ((q ^ ((rowA >> 1) & 3)) * 8));
        }
        #pragma unroll
        for (int j = 0; j < 4; j++) {
            int rowB = j * 16 + rr;
            bfr[j] = *(const bf16x8*)(sB + rowB * 32 + ((q ^ ((rowB >> 1) & 3)) * 8));
        }
        #pragma unroll
        for (int i = 0; i < 2; i++)
            #pragma unroll
            for (int j = 0; j < 4; j++)
                acc[i][j] = __builtin_amdgcn_mfma_f32_16x16x32_bf16(af[i], bfr[j], acc[i][j], 0, 0, 0);
    }

    #pragma unroll
    for (int i = 0; i < 2; i++) {
        #pragma unroll
        for (int j = 0; j < 4; j++) {
            int col = n0 + j * 16 + rr;
            #pragma unroll
            for (int jj = 0; jj < 4; jj++) {
                int row = m0 + w * 32 + i * 16 + q * 4 + jj;
                C[(size_t)row * N + col] = acc[i][j][jj];
            }
        }
    }
}

// ---------------------------------------------------------------------------
// Causal depthwise conv (K=4) + bias + SiLU, vectorized.
// ---------------------------------------------------------------------------
__global__ void conv_silu(const __bf16* __restrict__ x, const float* __restrict__ cwT,
                          const float* __restrict__ bias, __bf16* __restrict__ xcB) {
    int row = blockIdx.x;          // 0..M_-1
    int d   = threadIdx.x * 8;     // 0..DM-8
    int l   = row % L_;
    size_t base = (size_t)row * DM + d;

    float acc[8];
    {
        const f32x4* b4 = (const f32x4*)(bias + d);
        f32x4 b0 = b4[0], b1 = b4[1];
        #pragma unroll
        for (int q = 0; q < 4; q++) { acc[q] = b0[q]; acc[4 + q] = b1[q]; }
    }
    #pragma unroll
    for (int i = 0; i < KC; i++) {
        int li = l - (KC - 1) + i;
        if (li >= 0) {                       // uniform across block
            bf16x8 xv = *(const bf16x8*)(x + base + (size_t)(i - (KC - 1)) * DM);
            const f32x4* w4 = (const f32x4*)(cwT + (size_t)i * DM + d);
            f32x4 w0 = w4[0], w1 = w4[1];
            #pragma unroll
            for (int q = 0; q < 4; q++) {
                acc[q]     = fmaf((float)xv[q],     w0[q], acc[q]);
                acc[4 + q] = fmaf((float)xv[4 + q], w1[q], acc[4 + q]);
            }
        }
    }
    bf16x8 out;
    #pragma unroll
    for (int q = 0; q < 8; q++) {
        float v = acc[q] / (1.f + __expf(-acc[q]));
        out[q] = (__bf16)v;
    }
    *(bf16x8*)(xcB + base) = out;
}

// ---------------------------------------------------------------------------
// Fused chunked scan (cooperative): phase1 -> grid.sync -> phase2 ->
// grid.sync -> phase3. 512 blocks x 256 threads (2 blocks/CU).
// B/C read from P (cols 0..16 / 16..32). Reuses Aval/sB/sC across p1/p3.
// ---------------------------------------------------------------------------
__global__ void scan_fused(const __bf16* __restrict__ delta, const __bf16* __restrict__ xc,
                           const float* __restrict__ P, const float* __restrict__ A_log,
                           const float* __restrict__ Dw, const __bf16* __restrict__ res,
                           __bf16* __restrict__ aprodB, __bf16* __restrict__ cendB,
                           __bf16* __restrict__ hinitB, __bf16* __restrict__ ybar) {
    cg::grid_group grid = cg::this_grid();

    int blk = blockIdx.x;
    int c   = blk % NC;
    int rem = blk / NC;
    int dmt = rem % (DM / 256);
    int b   = rem / (DM / 256);
    int t   = threadIdx.x;
    int dm  = dmt * 256 + t;
    int l0  = c * CL;

    __shared__ float sB[CL * DS];      // 2 KB
    __shared__ float sC[CL * DS];      // 2 KB
    {
        size_t prow0 = ((size_t)b * L_ + l0 + (t >> 4)) * NP2;
        size_t prow1 = ((size_t)b * L_ + l0 + 16 + (t >> 4)) * NP2;
        int cidx = t & 15;
        sB[t]       = P[prow0 + cidx];
        sB[t + 256] = P[prow1 + cidx];
        sC[t]       = P[prow0 + 16 + cidx];
        sC[t + 256] = P[prow1 + 16 + cidx];
    }
    __syncthreads();

    float Aval[DS];
    {
        const f32x4* Ap = (const f32x4*)(A_log + (size_t)dm * DS);
        #pragma unroll
        for (int r4 = 0; r4 < 4; r4++) {
            f32x4 a = Ap[r4];
            #pragma unroll
            for (int q = 0; q < 4; q++) Aval[r4 * 4 + q] = -__expf(a[q]);
        }
    }
    float Dval = Dw[dm];

    size_t base = ((size_t)b * L_ + l0) * DM + dm;
    size_t s = ((size_t)(b * DM + dm)) * DS;

    // ---- phase 1: chunk-local (prod dA, end h) with h_in = 0 ----
    {
        float h[DS], ap[DS];
        #pragma unroll
        for (int i = 0; i < DS; i++) { h[i] = 0.f; ap[i] = 1.f; }

        #pragma unroll 4
        for (int j = 0; j < CL; j++) {
            float dl  = (float)delta[base + (size_t)j * DM];
            float xv  = (float)xc[base + (size_t)j * DM];
            float cmn = dl * xv;
            const f32x4* sB4 = (const f32x4*)(sB + j * DS);
            #pragma unroll
            for (int r4 = 0; r4 < 4; r4++) {
                f32x4 bv = sB4[r4];
                #pragma unroll
                for (int q = 0; q < 4; q++) {
                    int i = r4 * 4 + q;
                    float dA = __expf(dl * Aval[i]);
                    ap[i] *= dA;
                    h[i] = fmaf(dA, h[i], cmn * bv[q]);
                }
            }
        }
        #pragma unroll
        for (int r8 = 0; r8 < 2; r8++) {
            bf16x8 va, vh;
            #pragma unroll
            for (int q = 0; q < 8; q++) { va[q] = (__bf16)ap[r8 * 8 + q]; vh[q] = (__bf16)h[r8 * 8 + q]; }
            ((bf16x8*)(aprodB + (size_t)c * S_ + s))[r8] = va;
            ((bf16x8*)(cendB  + (size_t)c * S_ + s))[r8] = vh;
        }
    }

    __threadfence();
    grid.sync();

    // ---- phase 2: scan the chunk summaries (32 blocks cover all states) ----
    if (blk < S_ / (256 * 8)) {
        int u8 = (blk * 256 + t) * 8;
        float h[8];
        #pragma unroll
        for (int q = 0; q < 8; q++) h[q] = 0.f;
        #pragma unroll
        for (int cc = 0; cc < NC; cc++) {
            bf16x8 a  = *(const bf16x8*)(aprodB + (size_t)cc * S_ + u8);
            bf16x8 ce = *(const bf16x8*)(cendB  + (size_t)cc * S_ + u8);
            bf16x8 ho;
            #pragma unroll
            for (int q = 0; q < 8; q++) {
                ho[q] = (__bf16)h[q];
                h[q] = fmaf((float)a[q], h[q], (float)ce[q]);
            }
            *(bf16x8*)(hinitB + (size_t)cc * S_ + u8) = ho;
        }
    }

    __threadfence();
    grid.sync();

    // ---- phase 3: replay from h_init, fused epilogue -> ybar bf16 ----
    {
        float h[DS];
        #pragma unroll
        for (int r8 = 0; r8 < 2; r8++) {
            bf16x8 v = ((const bf16x8*)(hinitB + (size_t)c * S_ + s))[r8];
            #pragma unroll
            for (int q = 0; q < 8; q++) h[r8 * 8 + q] = (float)v[q];
        }

        #pragma unroll 4
        for (int j = 0; j < CL; j++) {
            float dl  = (float)delta[base + (size_t)j * DM];
            float xv  = (float)xc[base + (size_t)j * DM];
            float rv  = (float)res[base + (size_t)j * DM];
            float cmn = dl * xv;
            float y = 0.f;
            const f32x4* sB4 = (const f32x4*)(sB + j * DS);
            const f32x4* sC4 = (const f32x4*)(sC + j * DS);
            #pragma unroll
            for (int r4 = 0; r4 < 4; r4++) {
                f32x4 bv = sB4[r4];
                f32x4 cv = sC4[r4];
                #pragma unroll
                for (int q = 0; q < 4; q++) {
                    int i = r4 * 4 + q;
                    float dA = __expf(dl * Aval[i]);
                    h[i] = fmaf(dA, h[i], cmn * bv[q]);
                    y = fmaf(h[i], cv[q], y);
                }
            }
            float g = rv / (1.f + __expf(-rv));
            ybar[base + (size_t)j * DM] = (__bf16)((y + Dval * xv) * g);
        }
    }
}

// ---------------------------------------------------------------------------
extern "C" void kernel_launch(void* const* d_in, const int* in_sizes, int n_in,
                              void* d_out, int out_size, void* d_ws, size_t ws_size,
                              hipStream_t stream) {
    // All reference tensors are float32.
    const float* x_in   = (const float*)d_in[0];
    const float* W_in   = (const float*)d_in[1];
    const float* W_res  = (const float*)d_in[2];
    const float* W_out  = (const float*)d_in[3];
    const float* conv_w = (const float*)d_in[4];
    const float* conv_b = (const float*)d_in[5];
    const float* A_log  = (const float*)d_in[6];
    const float* Dw     = (const float*)d_in[7];
    const float* W_B    = (const float*)d_in[8];
    const float* W_C    = (const float*)d_in[9];
    const float* W_dt   = (const float*)d_in[10];
    const float* dt_w   = (const float*)d_in[11];
    const float* dt_b   = (const float*)d_in[12];

    // ---------------- Workspace layout ----------------
    float* ws_f = (float*)d_ws;
    float* P     = ws_f;                        // M_*NP2 f32 (proj accumulator: B|C|dtmp)
    float* cwT   = P + (size_t)M_ * NP2;        // KC*DM
    __bf16* bf_base = (__bf16*)(cwT + (size_t)KC * DM);
    __bf16* ybar   = bf_base;                   // M_*DM
    __bf16* xinB   = ybar   + (size_t)M_ * DM;  // M_*DIN
    __bf16* WinT   = xinB   + (size_t)M_ * DIN; // DM*DIN } adjacent: fused (4096 x DIN) BT
    __bf16* WresT  = WinT   + (size_t)DM * DIN; // DM*DIN }
    __bf16* WoutT  = WresT  + (size_t)DM * DIN; // DIN*DM
    __bf16* xB     = WoutT  + (size_t)DIN * DM; // M_*DM (conv input, bf16)
    __bf16* xcB    = xB     + (size_t)M_ * DM;  // M_*DM
    __bf16* projW  = xcB    + (size_t)M_ * DM;  // NP2*DM
    __bf16* dtwT   = projW  + (size_t)NP2 * DM; // DM*DR
    __bf16* deltaB = dtwT   + (size_t)DM * DR;  // M_*DM
    __bf16* resB   = deltaB + (size_t)M_ * DM;  // M_*DM
    __bf16* aprodB = resB   + (size_t)M_ * DM;  // NC*S_
    __bf16* cendB  = aprodB + (size_t)NC * S_;  // NC*S_
    __bf16* hinitB = cendB  + (size_t)NC * S_;  // NC*S_

    // ---------------- fused operand prep (1 launch) ----------------
    prep_all<<<17184, 256, 0, stream>>>(x_in, W_in, W_res, W_out, dt_w, W_B, W_C, W_dt,
                                        conv_w, xinB, WinT, WresT, WoutT, dtwT, projW,
                                        cwT, P);

    // Fused input GEMMs: [x (bf16) | res (bf16)] = x_in @ [W_in | W_res]
    gemm_tile128<2><<<dim3((2 * DM) / 128, M_ / 128, 1), 256, 0, stream>>>(
        xinB, WinT, (float*)xB, resB, nullptr, M_, 2 * DM, DIN, DIN, DIN);

    conv_silu<<<M_, 256, 0, stream>>>(xB, cwT, conv_b, xcB);

    // Packed projections, split-K with atomic accumulate into P (cols < 160)
    gemm_tile128<3><<<dim3(NP2 / 128, M_ / 128, KSLICES), 256, 0, stream>>>(
        xcB, projW, P, nullptr, nullptr, M_, NP2, KSL, DM, DM);

    // delta = softplus(dtmp @ dt_w + dt_b) -> bf16 (A = f32 direct from P)
    gemm_delta<<<dim3(DM / 128, M_ / 128), 256, 0, stream>>>(
        P, dtwT, dt_b, deltaB, M_, DM);

    // Fused chunked selective scan (cooperative: p1 -> sync -> p2 -> sync -> p3)
    {
        void* args[] = {(void*)&deltaB, (void*)&xcB, (void*)&P, (void*)&A_log,
                        (void*)&Dw, (void*)&resB, (void*)&aprodB, (void*)&cendB,
                        (void*)&hinitB, (void*)&ybar};
        hipLaunchCooperativeKernel((void*)scan_fused, dim3(B_ * (DM / 256) * NC), dim3(256),
                                   args, 0, stream);
    }

    // out = ybar @ W_out  (M_ x DIN, K=DM), direct f32 store, 256 blocks
    gemm_out64<<<dim3(DIN / 64, M_ / 128), 256, 0, stream>>>(
        ybar, WoutT, (float*)d_out, M_, DIN, DM, DM, DM);
}

// Round 12
// 281.914 us; speedup vs baseline: 1.8039x; 1.8039x over previous
//
#include <hip/hip_runtime.h>
#include <hip/hip_bf16.h>

// Problem constants
constexpr int B_  = 2;
constexpr int L_  = 1024;
constexpr int DIN = 1024;
constexpr int DM  = 2048;
constexpr int DS  = 16;
constexpr int DR  = 128;
constexpr int KC  = 4;       // conv kernel size
constexpr int M_  = B_ * L_; // 2048 rows
constexpr int NP2 = 256;     // packed projection width (16+16+128 padded to 256)
constexpr int KSLICES = 8;   // split-K for proj GEMM (K slice = 256)
constexpr int KSL = DM / KSLICES;     // 256

// Chunked scan parameters
constexpr int NC = 32;               // number of chunks
constexpr int CL = L_ / NC;          // chunk length (32)
constexpr int S_ = B_ * DM * DS;     // 65536 scan states

typedef __bf16 bf16x8 __attribute__((ext_vector_type(8)));
typedef float  f32x4  __attribute__((ext_vector_type(4)));

// ---------------------------------------------------------------------------
// async global->LDS 16B copy (global_load_lds_dwordx4).
// ---------------------------------------------------------------------------
__device__ __forceinline__ void gload_lds16(const void* g, void* l) {
    __builtin_amdgcn_global_load_lds(
        (const __attribute__((address_space(1))) void*)g,
        (__attribute__((address_space(3))) void*)l, 16, 0, 0);
}

// ---------------------------------------------------------------------------
// Fused operand prep (one launch): convert + 4 transposes + proj pack +
// conv-weight transpose + zero the P accumulator (for proj atomics).
// ---------------------------------------------------------------------------
__device__ __forceinline__ void transpose_block(const float* __restrict__ in,
                                                __bf16* __restrict__ out,
                                                int R, int C, int bx, int by, int t) {
    __shared__ float tile[32][33];
    int tx = t & 31, ty = t >> 5;   // (32, 8)
    #pragma unroll
    for (int j = 0; j < 32; j += 8)
        tile[ty + j][tx] = in[(size_t)(by * 32 + ty + j) * C + (bx * 32 + tx)];
    __syncthreads();
    #pragma unroll
    for (int j = 0; j < 32; j += 8)
        out[(size_t)(bx * 32 + ty + j) * R + (by * 32 + tx)] = (__bf16)tile[tx][ty + j];
}

__global__ void prep_all(const float* __restrict__ x_in, const float* __restrict__ W_in,
                         const float* __restrict__ W_res, const float* __restrict__ W_out,
                         const float* __restrict__ dt_w,
                         const float* __restrict__ W_B, const float* __restrict__ W_C,
                         const float* __restrict__ W_dt, const float* __restrict__ conv_w,
                         __bf16* __restrict__ xinB, __bf16* __restrict__ WinT,
                         __bf16* __restrict__ WresT, __bf16* __restrict__ WoutT,
                         __bf16* __restrict__ dtwT, __bf16* __restrict__ projW,
                         float* __restrict__ cwT, float* __restrict__ P) {
    int blk = blockIdx.x, t = threadIdx.x;
    if (blk < 8192) {
        int i = blk * 256 + t;
        xinB[i] = (__bf16)x_in[i];
    } else if (blk < 10240) {
        int b = blk - 8192;                       // grid (64, 32)
        transpose_block(W_in, WinT, DIN, DM, b % 64, b / 64, t);
    } else if (blk < 12288) {
        int b = blk - 10240;
        transpose_block(W_res, WresT, DIN, DM, b % 64, b / 64, t);
    } else if (blk < 14336) {
        int b = blk - 12288;                      // grid (32, 64)
        transpose_block(W_out, WoutT, DM, DIN, b % 32, b / 32, t);
    } else if (blk < 14592) {
        int b = blk - 14336;                      // grid (64, 4)
        transpose_block(dt_w, dtwT, DR, DM, b % 64, b / 64, t);
    } else if (blk < 16640) {
        int i = (blk - 14592) * 256 + t;          // 0 .. NP2*DM
        int k = i % DM;
        int n = i / DM;
        float v = 0.f;
        if (n < 16)        v = W_B[(size_t)k * DS + n];
        else if (n < 32)   v = W_C[(size_t)k * DS + (n - 16)];
        else if (n < 160)  v = W_dt[(size_t)k * DR + (n - 32)];
        projW[i] = (__bf16)v;
    } else if (blk < 16672) {
        int j = (blk - 16640) * 256 + t;          // 0 .. KC*DM
        int tap = j / DM, d = j % DM;
        cwT[j] = conv_w[d * KC + tap];
    } else {
        int i = (blk - 16672) * 256 + t;          // 0 .. M_*NP2/4
        ((f32x4*)P)[i] = f32x4{0.f, 0.f, 0.f, 0.f};
    }
}

// ---------------------------------------------------------------------------
// m97-style MFMA GEMM: 128x128 block tile, BK=32, LDS-staged via
// global_load_lds width=16, XOR-swizzled slots. 4 waves, each 64x64.
// EPI: 0 = plain f32 partial store (stride N, z-slice offset);
//      1 = +bias[col], softplus -> bf16 Cb (stride N);
//      2 = dual-output bf16: col<DM -> (bf16*)Cf (x), else -> Cb (res), stride DM;
//      3 = split-K accumulate: atomicAdd into Cf (stride N), only col<160.
// ---------------------------------------------------------------------------
template<int EPI>
__global__ void gemm_tile128(const __bf16* __restrict__ A, const __bf16* __restrict__ BT,
                             float* __restrict__ Cf, __bf16* __restrict__ Cb,
                             const float* __restrict__ bias, int M, int N, int K,
                             int lda, int ldb) {
    __shared__ __bf16 sA[128 * 32];
    __shared__ __bf16 sB[128 * 32];
    int t = threadIdx.x;
    int lane = t & 63, w = t >> 6;
    int wm = w >> 1, wn = w & 1;
    int m0 = blockIdx.y * 128, n0 = blockIdx.x * 128;
    int kbase = blockIdx.z * K;
    int q = lane >> 4, rr = lane & 15;

    f32x4 acc[4][4] = {};

    int srow = t >> 2;          // 0..63 (staging row, +64 on round 1)
    int slot = t & 3;           // physical 8-elem slot within the 32-wide k

    for (int kt = 0; kt < K; kt += 32) {
        __syncthreads();
        #pragma unroll
        for (int rnd = 0; rnd < 2; rnd++) {
            int row = srow + rnd * 64;
            int gkb = slot ^ ((row >> 1) & 3);          // logical k-block fetched into this slot
            const __bf16* ga = A  + (size_t)(m0 + row) * lda + kbase + kt + gkb * 8;
            const __bf16* gb = BT + (size_t)(n0 + row) * ldb + kbase + kt + gkb * 8;
            __bf16* la = sA + rnd * 2048 + w * 512;     // wave-uniform base
            __bf16* lb = sB + rnd * 2048 + w * 512;
            gload_lds16(ga, la);
            gload_lds16(gb, lb);
        }
        __syncthreads();

        bf16x8 af[4], bfr[4];
        #pragma unroll
        for (int i = 0; i < 4; i++) {
            int rowA = wm * 64 + i * 16 + rr;
            af[i] = *(const bf16x8*)(sA + rowA * 32 + ((q ^ ((rowA >> 1) & 3)) * 8));
            int rowB = wn * 64 + i * 16 + rr;
            bfr[i] = *(const bf16x8*)(sB + rowB * 32 + ((q ^ ((rowB >> 1) & 3)) * 8));
        }
        #pragma unroll
        for (int i = 0; i < 4; i++)
            #pragma unroll
            for (int j = 0; j < 4; j++)
                acc[i][j] = __builtin_amdgcn_mfma_f32_16x16x32_bf16(af[i], bfr[j], acc[i][j], 0, 0, 0);
    }

    float* Cz = Cf + (size_t)blockIdx.z * M * N;
    #pragma unroll
    for (int i = 0; i < 4; i++) {
        #pragma unroll
        for (int j = 0; j < 4; j++) {
            int col = n0 + wn * 64 + j * 16 + rr;
            #pragma unroll
            for (int jj = 0; jj < 4; jj++) {
                int row = m0 + wm * 64 + i * 16 + q * 4 + jj;
                float v = acc[i][j][jj];
                if (EPI == 0) {
                    Cz[(size_t)row * N + col] = v;
                } else if (EPI == 1) {
                    float z = v + bias[col];
                    Cb[(size_t)row * N + col] = (__bf16)((z > 20.f) ? z : log1pf(__expf(z)));
                } else if (EPI == 2) {
                    if (col < DM) ((__bf16*)Cf)[(size_t)row * DM + col] = (__bf16)v;
                    else          Cb[(size_t)row * DM + (col - DM)] = (__bf16)v;
                } else {
                    if (col < 160) atomicAdd(&Cf[(size_t)row * N + col], v);
                }
            }
        }
    }
}

// ---------------------------------------------------------------------------
// delta GEMM: delta = softplus(dtmp @ dt_w + dt_b) -> bf16.
// A = dtmp is f32 in P cols [32,160); direct global loads + in-reg bf16 cvt.
// ---------------------------------------------------------------------------
__global__ void gemm_delta(const float* __restrict__ P, const __bf16* __restrict__ BT,
                           const float* __restrict__ bias, __bf16* __restrict__ Cb,
                           int M, int N) {
    __shared__ __bf16 sB[128 * 32];
    int t = threadIdx.x;
    int lane = t & 63, w = t >> 6;
    int wm = w >> 1, wn = w & 1;
    int m0 = blockIdx.y * 128, n0 = blockIdx.x * 128;
    int q = lane >> 4, rr = lane & 15;

    f32x4 acc[4][4] = {};
    int srow = t >> 2;
    int slot = t & 3;

    for (int kt = 0; kt < DR; kt += 32) {
        __syncthreads();
        #pragma unroll
        for (int rnd = 0; rnd < 2; rnd++) {
            int row = srow + rnd * 64;
            int gkb = slot ^ ((row >> 1) & 3);
            const __bf16* gb = BT + (size_t)(n0 + row) * DR + kt + gkb * 8;
            __bf16* lb = sB + rnd * 2048 + w * 512;
            gload_lds16(gb, lb);
        }
        __syncthreads();

        bf16x8 af[4], bfr[4];
        #pragma unroll
        for (int i = 0; i < 4; i++) {
            int rowA = m0 + wm * 64 + i * 16 + rr;
            const f32x4* ap = (const f32x4*)(P + (size_t)rowA * NP2 + 32 + kt + q * 8);
            f32x4 a0 = ap[0], a1 = ap[1];
            bf16x8 av;
            #pragma unroll
            for (int c = 0; c < 4; c++) { av[c] = (__bf16)a0[c]; av[4 + c] = (__bf16)a1[c]; }
            af[i] = av;
            int rowB = wn * 64 + i * 16 + rr;
            bfr[i] = *(const bf16x8*)(sB + rowB * 32 + ((q ^ ((rowB >> 1) & 3)) * 8));
        }
        #pragma unroll
        for (int i = 0; i < 4; i++)
            #pragma unroll
            for (int j = 0; j < 4; j++)
                acc[i][j] = __builtin_amdgcn_mfma_f32_16x16x32_bf16(af[i], bfr[j], acc[i][j], 0, 0, 0);
    }

    #pragma unroll
    for (int i = 0; i < 4; i++) {
        #pragma unroll
        for (int j = 0; j < 4; j++) {
            int col = n0 + wn * 64 + j * 16 + rr;
            float bz = bias[col];
            #pragma unroll
            for (int jj = 0; jj < 4; jj++) {
                int row = m0 + wm * 64 + i * 16 + q * 4 + jj;
                float z = acc[i][j][jj] + bz;
                Cb[(size_t)row * N + col] = (__bf16)((z > 20.f) ? z : log1pf(__expf(z)));
            }
        }
    }
}

// ---------------------------------------------------------------------------
// Out GEMM: 128(M)x64(N) tile, 4 waves each 32x64, direct f32 store.
// ---------------------------------------------------------------------------
__global__ void gemm_out64(const __bf16* __restrict__ A, const __bf16* __restrict__ BT,
                           float* __restrict__ C, int M, int N, int K, int lda, int ldb) {
    __shared__ __bf16 sA[128 * 32];
    __shared__ __bf16 sB[64 * 32];
    int t = threadIdx.x;
    int lane = t & 63, w = t >> 6;
    int m0 = blockIdx.y * 128, n0 = blockIdx.x * 64;
    int q = lane >> 4, rr = lane & 15;

    f32x4 acc[2][4] = {};
    int srow = t >> 2;
    int slot = t & 3;

    for (int kt = 0; kt < K; kt += 32) {
        __syncthreads();
        #pragma unroll
        for (int rnd = 0; rnd < 2; rnd++) {
            int row = srow + rnd * 64;
            int gkb = slot ^ ((row >> 1) & 3);
            const __bf16* ga = A + (size_t)(m0 + row) * lda + kt + gkb * 8;
            __bf16* la = sA + rnd * 2048 + w * 512;
            gload_lds16(ga, la);
        }
        {
            int row = srow;
            int gkb = slot ^ ((row >> 1) & 3);
            const __bf16* gb = BT + (size_t)(n0 + row) * ldb + kt + gkb * 8;
            __bf16* lb = sB + w * 512;
            gload_lds16(gb, lb);
        }
        __syncthreads();

        bf16x8 af[2], bfr[4];
        #pragma unroll
        for (int i = 0; i < 2; i++) {
            int rowA = w * 32 + i * 16 + rr;
            af[i] = *(const bf16x8*)(sA + rowA * 32 + ((q ^ ((rowA >> 1) & 3)) * 8));
        }
        #pragma unroll
        for (int j = 0; j < 4; j++) {
            int rowB = j * 16 + rr;
            bfr[j] = *(const bf16x8*)(sB + rowB * 32 + ((q ^ ((rowB >> 1) & 3)) * 8));
        }
        #pragma unroll
        for (int i = 0; i < 2; i++)
            #pragma unroll
            for (int j = 0; j < 4; j++)
                acc[i][j] = __builtin_amdgcn_mfma_f32_16x16x32_bf16(af[i], bfr[j], acc[i][j], 0, 0, 0);
    }

    #pragma unroll
    for (int i = 0; i < 2; i++) {
        #pragma unroll
        for (int j = 0; j < 4; j++) {
            int col = n0 + j * 16 + rr;
            #pragma unroll
            for (int jj = 0; jj < 4; jj++) {
                int row = m0 + w * 32 + i * 16 + q * 4 + jj;
                C[(size_t)row * N + col] = acc[i][j][jj];
            }
        }
    }
}

// ---------------------------------------------------------------------------
// Causal depthwise conv (K=4) + bias + SiLU, vectorized.
// ---------------------------------------------------------------------------
__global__ void conv_silu(const __bf16* __restrict__ x, const float* __restrict__ cwT,
                          const float* __restrict__ bias, __bf16* __restrict__ xcB) {
    int row = blockIdx.x;          // 0..M_-1
    int d   = threadIdx.x * 8;     // 0..DM-8
    int l   = row % L_;
    size_t base = (size_t)row * DM + d;

    float acc[8];
    {
        const f32x4* b4 = (const f32x4*)(bias + d);
        f32x4 b0 = b4[0], b1 = b4[1];
        #pragma unroll
        for (int q = 0; q < 4; q++) { acc[q] = b0[q]; acc[4 + q] = b1[q]; }
    }
    #pragma unroll
    for (int i = 0; i < KC; i++) {
        int li = l - (KC - 1) + i;
        if (li >= 0) {                       // uniform across block
            bf16x8 xv = *(const bf16x8*)(x + base + (size_t)(i - (KC - 1)) * DM);
            const f32x4* w4 = (const f32x4*)(cwT + (size_t)i * DM + d);
            f32x4 w0 = w4[0], w1 = w4[1];
            #pragma unroll
            for (int q = 0; q < 4; q++) {
                acc[q]     = fmaf((float)xv[q],     w0[q], acc[q]);
                acc[4 + q] = fmaf((float)xv[4 + q], w1[q], acc[4 + q]);
            }
        }
    }
    bf16x8 out;
    #pragma unroll
    for (int q = 0; q < 8; q++) {
        float v = acc[q] / (1.f + __expf(-acc[q]));
        out[q] = (__bf16)v;
    }
    *(bf16x8*)(xcB + base) = out;
}

// ---------------------------------------------------------------------------
// Chunked scan, phase 1. Thread owns one (b, dm, chunk): 16 ds states in regs.
// B read from P cols [0,16). Summaries written bf16.
// ---------------------------------------------------------------------------
__global__ void scan_phase1(const __bf16* __restrict__ delta, const __bf16* __restrict__ xc,
                            const float* __restrict__ P, const float* __restrict__ A_log,
                            __bf16* __restrict__ aprodB, __bf16* __restrict__ cendB) {
    int blk = blockIdx.x;
    int c   = blk % NC;
    int rem = blk / NC;
    int dmt = rem % (DM / 256);
    int b   = rem / (DM / 256);
    int t   = threadIdx.x;
    int dm  = dmt * 256 + t;
    int l0  = c * CL;

    __shared__ float sB[CL * DS];      // 2 KB
    {
        size_t prow0 = ((size_t)b * L_ + l0 + (t >> 4)) * NP2;
        size_t prow1 = ((size_t)b * L_ + l0 + 16 + (t >> 4)) * NP2;
        int cidx = t & 15;
        sB[t]       = P[prow0 + cidx];
        sB[t + 256] = P[prow1 + cidx];
    }
    __syncthreads();

    float Aval[DS];
    {
        const f32x4* Ap = (const f32x4*)(A_log + (size_t)dm * DS);
        #pragma unroll
        for (int r4 = 0; r4 < 4; r4++) {
            f32x4 a = Ap[r4];
            #pragma unroll
            for (int q = 0; q < 4; q++) Aval[r4 * 4 + q] = -__expf(a[q]);
        }
    }

    float h[DS], ap[DS];
    #pragma unroll
    for (int i = 0; i < DS; i++) { h[i] = 0.f; ap[i] = 1.f; }

    size_t base = ((size_t)b * L_ + l0) * DM + dm;
    #pragma unroll 4
    for (int j = 0; j < CL; j++) {
        float dl  = (float)delta[base + (size_t)j * DM];
        float xv  = (float)xc[base + (size_t)j * DM];
        float cmn = dl * xv;
        const f32x4* sB4 = (const f32x4*)(sB + j * DS);
        #pragma unroll
        for (int r4 = 0; r4 < 4; r4++) {
            f32x4 bv = sB4[r4];
            #pragma unroll
            for (int q = 0; q < 4; q++) {
                int i = r4 * 4 + q;
                float dA = __expf(dl * Aval[i]);
                ap[i] *= dA;
                h[i] = fmaf(dA, h[i], cmn * bv[q]);
            }
        }
    }

    size_t s = ((size_t)(b * DM + dm)) * DS;
    #pragma unroll
    for (int r8 = 0; r8 < 2; r8++) {
        bf16x8 va, vh;
        #pragma unroll
        for (int q = 0; q < 8; q++) { va[q] = (__bf16)ap[r8 * 8 + q]; vh[q] = (__bf16)h[r8 * 8 + q]; }
        ((bf16x8*)(aprodB + (size_t)c * S_ + s))[r8] = va;
        ((bf16x8*)(cendB  + (size_t)c * S_ + s))[r8] = vh;
    }
}

// ---------------------------------------------------------------------------
// Chunked scan, phase 2: scan chunk summaries (bf16 in/out, f32 math).
// ---------------------------------------------------------------------------
__global__ void scan_phase2(const __bf16* __restrict__ aprodB, const __bf16* __restrict__ cendB,
                            __bf16* __restrict__ hinitB) {
    int u8 = (blockIdx.x * 256 + threadIdx.x) * 8;   // 0..S_-8
    float h[8];
    #pragma unroll
    for (int q = 0; q < 8; q++) h[q] = 0.f;
    #pragma unroll
    for (int c = 0; c < NC; c++) {
        bf16x8 a  = *(const bf16x8*)(aprodB + (size_t)c * S_ + u8);
        bf16x8 ce = *(const bf16x8*)(cendB  + (size_t)c * S_ + u8);
        bf16x8 ho;
        #pragma unroll
        for (int q = 0; q < 8; q++) {
            ho[q] = (__bf16)h[q];
            h[q] = fmaf((float)a[q], h[q], (float)ce[q]);
        }
        *(bf16x8*)(hinitB + (size_t)c * S_ + u8) = ho;
    }
}

// ---------------------------------------------------------------------------
// Chunked scan, phase 3: replay from h_init, fused epilogue -> bf16.
// B/C read from P cols [0,16)/[16,32).
// ---------------------------------------------------------------------------
__global__ void scan_phase3(const __bf16* __restrict__ delta, const __bf16* __restrict__ xc,
                            const float* __restrict__ P, const __bf16* __restrict__ res,
                            const float* __restrict__ A_log, const float* __restrict__ Dw,
                            const __bf16* __restrict__ hinitB, __bf16* __restrict__ ybar) {
    int blk = blockIdx.x;
    int c   = blk % NC;
    int rem = blk / NC;
    int dmt = rem % (DM / 256);
    int b   = rem / (DM / 256);
    int t   = threadIdx.x;
    int dm  = dmt * 256 + t;
    int l0  = c * CL;

    __shared__ float sB[CL * DS];      // 2 KB
    __shared__ float sC[CL * DS];      // 2 KB
    {
        size_t prow0 = ((size_t)b * L_ + l0 + (t >> 4)) * NP2;
        size_t prow1 = ((size_t)b * L_ + l0 + 16 + (t >> 4)) * NP2;
        int cidx = t & 15;
        sB[t]       = P[prow0 + cidx];
        sB[t + 256] = P[prow1 + cidx];
        sC[t]       = P[prow0 + 16 + cidx];
        sC[t + 256] = P[prow1 + 16 + cidx];
    }
    __syncthreads();

    float Aval[DS];
    {
        const f32x4* Ap = (const f32x4*)(A_log + (size_t)dm * DS);
        #pragma unroll
        for (int r4 = 0; r4 < 4; r4++) {
            f32x4 a = Ap[r4];
            #pragma unroll
            for (int q = 0; q < 4; q++) Aval[r4 * 4 + q] = -__expf(a[q]);
        }
    }
    float Dval = Dw[dm];

    float h[DS];
    {
        size_t s = ((size_t)(b * DM + dm)) * DS;
        #pragma unroll
        for (int r8 = 0; r8 < 2; r8++) {
            bf16x8 v = ((const bf16x8*)(hinitB + (size_t)c * S_ + s))[r8];
            #pragma unroll
            for (int q = 0; q < 8; q++) h[r8 * 8 + q] = (float)v[q];
        }
    }

    size_t base = ((size_t)b * L_ + l0) * DM + dm;
    #pragma unroll 4
    for (int j = 0; j < CL; j++) {
        float dl  = (float)delta[base + (size_t)j * DM];
        float xv  = (float)xc[base + (size_t)j * DM];
        float rv  = (float)res[base + (size_t)j * DM];
        float cmn = dl * xv;
        float y = 0.f;
        const f32x4* sB4 = (const f32x4*)(sB + j * DS);
        const f32x4* sC4 = (const f32x4*)(sC + j * DS);
        #pragma unroll
        for (int r4 = 0; r4 < 4; r4++) {
            f32x4 bv = sB4[r4];
            f32x4 cv = sC4[r4];
            #pragma unroll
            for (int q = 0; q < 4; q++) {
                int i = r4 * 4 + q;
                float dA = __expf(dl * Aval[i]);
                h[i] = fmaf(dA, h[i], cmn * bv[q]);
                y = fmaf(h[i], cv[q], y);
            }
        }
        float g = rv / (1.f + __expf(-rv));
        ybar[base + (size_t)j * DM] = (__bf16)((y + Dval * xv) * g);
    }
}

// ---------------------------------------------------------------------------
extern "C" void kernel_launch(void* const* d_in, const int* in_sizes, int n_in,
                              void* d_out, int out_size, void* d_ws, size_t ws_size,
                              hipStream_t stream) {
    // All reference tensors are float32.
    const float* x_in   = (const float*)d_in[0];
    const float* W_in   = (const float*)d_in[1];
    const float* W_res  = (const float*)d_in[2];
    const float* W_out  = (const float*)d_in[3];
    const float* conv_w = (const float*)d_in[4];
    const float* conv_b = (const float*)d_in[5];
    const float* A_log  = (const float*)d_in[6];
    const float* Dw     = (const float*)d_in[7];
    const float* W_B    = (const float*)d_in[8];
    const float* W_C    = (const float*)d_in[9];
    const float* W_dt   = (const float*)d_in[10];
    const float* dt_w   = (const float*)d_in[11];
    const float* dt_b   = (const float*)d_in[12];

    // ---------------- Workspace layout ----------------
    float* ws_f = (float*)d_ws;
    float* P     = ws_f;                        // M_*NP2 f32 (proj accumulator: B|C|dtmp)
    float* cwT   = P + (size_t)M_ * NP2;        // KC*DM
    __bf16* bf_base = (__bf16*)(cwT + (size_t)KC * DM);
    __bf16* ybar   = bf_base;                   // M_*DM
    __bf16* xinB   = ybar   + (size_t)M_ * DM;  // M_*DIN
    __bf16* WinT   = xinB   + (size_t)M_ * DIN; // DM*DIN } adjacent: fused (4096 x DIN) BT
    __bf16* WresT  = WinT   + (size_t)DM * DIN; // DM*DIN }
    __bf16* WoutT  = WresT  + (size_t)DM * DIN; // DIN*DM
    __bf16* xB     = WoutT  + (size_t)DIN * DM; // M_*DM (conv input, bf16)
    __bf16* xcB    = xB     + (size_t)M_ * DM;  // M_*DM
    __bf16* projW  = xcB    + (size_t)M_ * DM;  // NP2*DM
    __bf16* dtwT   = projW  + (size_t)NP2 * DM; // DM*DR
    __bf16* deltaB = dtwT   + (size_t)DM * DR;  // M_*DM
    __bf16* resB   = deltaB + (size_t)M_ * DM;  // M_*DM
    __bf16* aprodB = resB   + (size_t)M_ * DM;  // NC*S_
    __bf16* cendB  = aprodB + (size_t)NC * S_;  // NC*S_
    __bf16* hinitB = cendB  + (size_t)NC * S_;  // NC*S_

    // ---------------- fused operand prep (1 launch) ----------------
    prep_all<<<17184, 256, 0, stream>>>(x_in, W_in, W_res, W_out, dt_w, W_B, W_C, W_dt,
                                        conv_w, xinB, WinT, WresT, WoutT, dtwT, projW,
                                        cwT, P);

    // Fused input GEMMs: [x (bf16) | res (bf16)] = x_in @ [W_in | W_res]
    gemm_tile128<2><<<dim3((2 * DM) / 128, M_ / 128, 1), 256, 0, stream>>>(
        xinB, WinT, (float*)xB, resB, nullptr, M_, 2 * DM, DIN, DIN, DIN);

    conv_silu<<<M_, 256, 0, stream>>>(xB, cwT, conv_b, xcB);

    // Packed projections, split-K with atomic accumulate into P (cols < 160)
    gemm_tile128<3><<<dim3(NP2 / 128, M_ / 128, KSLICES), 256, 0, stream>>>(
        xcB, projW, P, nullptr, nullptr, M_, NP2, KSL, DM, DM);

    // delta = softplus(dtmp @ dt_w + dt_b) -> bf16 (A = f32 direct from P)
    gemm_delta<<<dim3(DM / 128, M_ / 128), 256, 0, stream>>>(
        P, dtwT, dt_b, deltaB, M_, DM);

    // Chunked selective scan (3 separate launches; kernel boundary = cheap barrier)
    int nblk = B_ * (DM / 256) * NC;   // 512
    scan_phase1<<<nblk, 256, 0, stream>>>(deltaB, xcB, P, A_log, aprodB, cendB);
    scan_phase2<<<S_ / (256 * 8), 256, 0, stream>>>(aprodB, cendB, hinitB);
    scan_phase3<<<nblk, 256, 0, stream>>>(deltaB, xcB, P, resB, A_log, Dw, hinitB, ybar);

    // out = ybar @ W_out  (M_ x DIN, K=DM), direct f32 store, 256 blocks
    gemm_out64<<<dim3(DIN / 64, M_ / 128), 256, 0, stream>>>(
        ybar, WoutT, (float*)d_out, M_, DIN, DM, DM, DM);
}

// Round 13
// 265.987 us; speedup vs baseline: 1.9119x; 1.0599x over previous
//
#include <hip/hip_runtime.h>
#include <hip/hip_bf16.h>

// Problem constants
constexpr int B_  = 2;
constexpr int L_  = 1024;
constexpr int DIN = 1024;
constexpr int DM  = 2048;
constexpr int DS  = 16;
constexpr int DR  = 128;
constexpr int KC  = 4;       // conv kernel size
constexpr int M_  = B_ * L_; // 2048 rows
constexpr int NP2 = 256;     // packed projection width (16+16+128 padded to 256)
constexpr int NPC = 160;     // compact packed width (16+16+128)
constexpr int KSLICES = 8;   // split-K for proj GEMM (K slice = 256)
constexpr int KSL = DM / KSLICES;     // 256

// Chunked scan parameters
constexpr int NC = 32;               // number of chunks
constexpr int CL = L_ / NC;          // chunk length (32)
constexpr int S_ = B_ * DM * DS;     // 65536 scan states

typedef __bf16 bf16x8 __attribute__((ext_vector_type(8)));
typedef float  f32x4  __attribute__((ext_vector_type(4)));

// ---------------------------------------------------------------------------
// async global->LDS 16B copy (global_load_lds_dwordx4).
// ---------------------------------------------------------------------------
__device__ __forceinline__ void gload_lds16(const void* g, void* l) {
    __builtin_amdgcn_global_load_lds(
        (const __attribute__((address_space(1))) void*)g,
        (__attribute__((address_space(3))) void*)l, 16, 0, 0);
}

// ---------------------------------------------------------------------------
// Fused operand prep (one launch): convert + 4 transposes + proj pack +
// conv-weight transpose.
// ---------------------------------------------------------------------------
__device__ __forceinline__ void transpose_block(const float* __restrict__ in,
                                                __bf16* __restrict__ out,
                                                int R, int C, int bx, int by, int t) {
    __shared__ float tile[32][33];
    int tx = t & 31, ty = t >> 5;   // (32, 8)
    #pragma unroll
    for (int j = 0; j < 32; j += 8)
        tile[ty + j][tx] = in[(size_t)(by * 32 + ty + j) * C + (bx * 32 + tx)];
    __syncthreads();
    #pragma unroll
    for (int j = 0; j < 32; j += 8)
        out[(size_t)(bx * 32 + ty + j) * R + (by * 32 + tx)] = (__bf16)tile[tx][ty + j];
}

__global__ void prep_all(const float* __restrict__ x_in, const float* __restrict__ W_in,
                         const float* __restrict__ W_res, const float* __restrict__ W_out,
                         const float* __restrict__ dt_w,
                         const float* __restrict__ W_B, const float* __restrict__ W_C,
                         const float* __restrict__ W_dt, const float* __restrict__ conv_w,
                         __bf16* __restrict__ xinB, __bf16* __restrict__ WinT,
                         __bf16* __restrict__ WresT, __bf16* __restrict__ WoutT,
                         __bf16* __restrict__ dtwT, __bf16* __restrict__ projW,
                         float* __restrict__ cwT) {
    int blk = blockIdx.x, t = threadIdx.x;
    if (blk < 8192) {
        int i = blk * 256 + t;
        xinB[i] = (__bf16)x_in[i];
    } else if (blk < 10240) {
        int b = blk - 8192;                       // grid (64, 32)
        transpose_block(W_in, WinT, DIN, DM, b % 64, b / 64, t);
    } else if (blk < 12288) {
        int b = blk - 10240;
        transpose_block(W_res, WresT, DIN, DM, b % 64, b / 64, t);
    } else if (blk < 14336) {
        int b = blk - 12288;                      // grid (32, 64)
        transpose_block(W_out, WoutT, DM, DIN, b % 32, b / 32, t);
    } else if (blk < 14592) {
        int b = blk - 14336;                      // grid (64, 4)
        transpose_block(dt_w, dtwT, DR, DM, b % 64, b / 64, t);
    } else if (blk < 16640) {
        int i = (blk - 14592) * 256 + t;          // 0 .. NP2*DM
        int k = i % DM;
        int n = i / DM;
        float v = 0.f;
        if (n < 16)        v = W_B[(size_t)k * DS + n];
        else if (n < 32)   v = W_C[(size_t)k * DS + (n - 16)];
        else if (n < 160)  v = W_dt[(size_t)k * DR + (n - 32)];
        projW[i] = (__bf16)v;
    } else {
        int j = (blk - 16640) * 256 + t;          // 0 .. KC*DM
        int tap = j / DM, d = j % DM;
        cwT[j] = conv_w[d * KC + tap];
    }
}

// ---------------------------------------------------------------------------
// Reduce proj split-K bf16 partials (dense stride NPC) and route:
// Bp, Cp (f32), dtmp (bf16). Fully coalesced.
// ---------------------------------------------------------------------------
__global__ void reduce_split(const __bf16* __restrict__ PpartB, float* __restrict__ Bp,
                             float* __restrict__ Cp, __bf16* __restrict__ dtmpB) {
    int i = blockIdx.x * 256 + threadIdx.x;   // 0 .. M_*NPC
    int row = i / NPC, c = i % NPC;
    float v = 0.f;
    #pragma unroll
    for (int ks = 0; ks < KSLICES; ks++)
        v += (float)PpartB[(size_t)ks * M_ * NPC + i];
    if (c < 16)       Bp[(size_t)row * DS + c] = v;
    else if (c < 32)  Cp[(size_t)row * DS + (c - 16)] = v;
    else              dtmpB[(size_t)row * DR + (c - 32)] = (__bf16)v;
}

// ---------------------------------------------------------------------------
// m97-style MFMA GEMM: 128x128 block tile, BK=32, LDS-staged via
// global_load_lds width=16, XOR-swizzled slots. 4 waves, each 64x64.
// EPI: 1 = +bias[col], softplus -> bf16 Cb (stride N);
//      2 = dual-output bf16: col<DM -> (bf16*)Cf (x), else -> Cb (res), stride DM;
//      4 = compact bf16 partial: col<NPC -> Cb + z*M*NPC, stride NPC.
// ---------------------------------------------------------------------------
template<int EPI>
__global__ void gemm_tile128(const __bf16* __restrict__ A, const __bf16* __restrict__ BT,
                             float* __restrict__ Cf, __bf16* __restrict__ Cb,
                             const float* __restrict__ bias, int M, int N, int K,
                             int lda, int ldb) {
    __shared__ __bf16 sA[128 * 32];
    __shared__ __bf16 sB[128 * 32];
    int t = threadIdx.x;
    int lane = t & 63, w = t >> 6;
    int wm = w >> 1, wn = w & 1;
    int m0 = blockIdx.y * 128, n0 = blockIdx.x * 128;
    int kbase = blockIdx.z * K;
    int q = lane >> 4, rr = lane & 15;

    f32x4 acc[4][4] = {};

    int srow = t >> 2;          // 0..63 (staging row, +64 on round 1)
    int slot = t & 3;           // physical 8-elem slot within the 32-wide k

    for (int kt = 0; kt < K; kt += 32) {
        __syncthreads();
        #pragma unroll
        for (int rnd = 0; rnd < 2; rnd++) {
            int row = srow + rnd * 64;
            int gkb = slot ^ ((row >> 1) & 3);          // logical k-block fetched into this slot
            const __bf16* ga = A  + (size_t)(m0 + row) * lda + kbase + kt + gkb * 8;
            const __bf16* gb = BT + (size_t)(n0 + row) * ldb + kbase + kt + gkb * 8;
            __bf16* la = sA + rnd * 2048 + w * 512;     // wave-uniform base
            __bf16* lb = sB + rnd * 2048 + w * 512;
            gload_lds16(ga, la);
            gload_lds16(gb, lb);
        }
        __syncthreads();

        bf16x8 af[4], bfr[4];
        #pragma unroll
        for (int i = 0; i < 4; i++) {
            int rowA = wm * 64 + i * 16 + rr;
            af[i] = *(const bf16x8*)(sA + rowA * 32 + ((q ^ ((rowA >> 1) & 3)) * 8));
            int rowB = wn * 64 + i * 16 + rr;
            bfr[i] = *(const bf16x8*)(sB + rowB * 32 + ((q ^ ((rowB >> 1) & 3)) * 8));
        }
        #pragma unroll
        for (int i = 0; i < 4; i++)
            #pragma unroll
            for (int j = 0; j < 4; j++)
                acc[i][j] = __builtin_amdgcn_mfma_f32_16x16x32_bf16(af[i], bfr[j], acc[i][j], 0, 0, 0);
    }

    #pragma unroll
    for (int i = 0; i < 4; i++) {
        #pragma unroll
        for (int j = 0; j < 4; j++) {
            int col = n0 + wn * 64 + j * 16 + rr;
            #pragma unroll
            for (int jj = 0; jj < 4; jj++) {
                int row = m0 + wm * 64 + i * 16 + q * 4 + jj;
                float v = acc[i][j][jj];
                if (EPI == 1) {
                    float z = v + bias[col];
                    Cb[(size_t)row * N + col] = (__bf16)((z > 20.f) ? z : log1pf(__expf(z)));
                } else if (EPI == 2) {
                    if (col < DM) ((__bf16*)Cf)[(size_t)row * DM + col] = (__bf16)v;
                    else          Cb[(size_t)row * DM + (col - DM)] = (__bf16)v;
                } else {
                    if (col < NPC)
                        Cb[(size_t)blockIdx.z * M * NPC + (size_t)row * NPC + col] = (__bf16)v;
                }
            }
        }
    }
}

// ---------------------------------------------------------------------------
// Out GEMM: 128(M)x64(N) tile, 4 waves each 32x64, direct f32 store.
// ---------------------------------------------------------------------------
__global__ void gemm_out64(const __bf16* __restrict__ A, const __bf16* __restrict__ BT,
                           float* __restrict__ C, int M, int N, int K, int lda, int ldb) {
    __shared__ __bf16 sA[128 * 32];
    __shared__ __bf16 sB[64 * 32];
    int t = threadIdx.x;
    int lane = t & 63, w = t >> 6;
    int m0 = blockIdx.y * 128, n0 = blockIdx.x * 64;
    int q = lane >> 4, rr = lane & 15;

    f32x4 acc[2][4] = {};
    int srow = t >> 2;
    int slot = t & 3;

    for (int kt = 0; kt < K; kt += 32) {
        __syncthreads();
        #pragma unroll
        for (int rnd = 0; rnd < 2; rnd++) {
            int row = srow + rnd * 64;
            int gkb = slot ^ ((row >> 1) & 3);
            const __bf16* ga = A + (size_t)(m0 + row) * lda + kt + gkb * 8;
            __bf16* la = sA + rnd * 2048 + w * 512;
            gload_lds16(ga, la);
        }
        {
            int row = srow;
            int gkb = slot ^ ((row >> 1) & 3);
            const __bf16* gb = BT + (size_t)(n0 + row) * ldb + kt + gkb * 8;
            __bf16* lb = sB + w * 512;
            gload_lds16(gb, lb);
        }
        __syncthreads();

        bf16x8 af[2], bfr[4];
        #pragma unroll
        for (int i = 0; i < 2; i++) {
            int rowA = w * 32 + i * 16 + rr;
            af[i] = *(const bf16x8*)(sA + rowA * 32 + ((q ^ ((rowA >> 1) & 3)) * 8));
        }
        #pragma unroll
        for (int j = 0; j < 4; j++) {
            int rowB = j * 16 + rr;
            bfr[j] = *(const bf16x8*)(sB + rowB * 32 + ((q ^ ((rowB >> 1) & 3)) * 8));
        }
        #pragma unroll
        for (int i = 0; i < 2; i++)
            #pragma unroll
            for (int j = 0; j < 4; j++)
                acc[i][j] = __builtin_amdgcn_mfma_f32_16x16x32_bf16(af[i], bfr[j], acc[i][j], 0, 0, 0);
    }

    #pragma unroll
    for (int i = 0; i < 2; i++) {
        #pragma unroll
        for (int j = 0; j < 4; j++) {
            int col = n0 + j * 16 + rr;
            #pragma unroll
            for (int jj = 0; jj < 4; jj++) {
                int row = m0 + w * 32 + i * 16 + q * 4 + jj;
                C[(size_t)row * N + col] = acc[i][j][jj];
            }
        }
    }
}

// ---------------------------------------------------------------------------
// Causal depthwise conv (K=4) + bias + SiLU, vectorized.
// ---------------------------------------------------------------------------
__global__ void conv_silu(const __bf16* __restrict__ x, const float* __restrict__ cwT,
                          const float* __restrict__ bias, __bf16* __restrict__ xcB) {
    int row = blockIdx.x;          // 0..M_-1
    int d   = threadIdx.x * 8;     // 0..DM-8
    int l   = row % L_;
    size_t base = (size_t)row * DM + d;

    float acc[8];
    {
        const f32x4* b4 = (const f32x4*)(bias + d);
        f32x4 b0 = b4[0], b1 = b4[1];
        #pragma unroll
        for (int q = 0; q < 4; q++) { acc[q] = b0[q]; acc[4 + q] = b1[q]; }
    }
    #pragma unroll
    for (int i = 0; i < KC; i++) {
        int li = l - (KC - 1) + i;
        if (li >= 0) {                       // uniform across block
            bf16x8 xv = *(const bf16x8*)(x + base + (size_t)(i - (KC - 1)) * DM);
            const f32x4* w4 = (const f32x4*)(cwT + (size_t)i * DM + d);
            f32x4 w0 = w4[0], w1 = w4[1];
            #pragma unroll
            for (int q = 0; q < 4; q++) {
                acc[q]     = fmaf((float)xv[q],     w0[q], acc[q]);
                acc[4 + q] = fmaf((float)xv[4 + q], w1[q], acc[4 + q]);
            }
        }
    }
    bf16x8 out;
    #pragma unroll
    for (int q = 0; q < 8; q++) {
        float v = acc[q] / (1.f + __expf(-acc[q]));
        out[q] = (__bf16)v;
    }
    *(bf16x8*)(xcB + base) = out;
}

// ---------------------------------------------------------------------------
// Chunked scan, phase 1. Thread owns one (b, dm, chunk): 16 ds states in regs.
// Dense coalesced Bp. Summaries written bf16.
// ---------------------------------------------------------------------------
__global__ void scan_phase1(const __bf16* __restrict__ delta, const __bf16* __restrict__ xc,
                            const float* __restrict__ Bp, const float* __restrict__ A_log,
                            __bf16* __restrict__ aprodB, __bf16* __restrict__ cendB) {
    int blk = blockIdx.x;
    int c   = blk % NC;
    int rem = blk / NC;
    int dmt = rem % (DM / 256);
    int b   = rem / (DM / 256);
    int t   = threadIdx.x;
    int dm  = dmt * 256 + t;
    int l0  = c * CL;

    __shared__ float sB[CL * DS];      // 2 KB
    sB[t]       = Bp[((size_t)b * L_ + l0) * DS + t];
    sB[t + 256] = Bp[((size_t)b * L_ + l0) * DS + t + 256];
    __syncthreads();

    float Aval[DS];
    {
        const f32x4* Ap = (const f32x4*)(A_log + (size_t)dm * DS);
        #pragma unroll
        for (int r4 = 0; r4 < 4; r4++) {
            f32x4 a = Ap[r4];
            #pragma unroll
            for (int q = 0; q < 4; q++) Aval[r4 * 4 + q] = -__expf(a[q]);
        }
    }

    float h[DS], ap[DS];
    #pragma unroll
    for (int i = 0; i < DS; i++) { h[i] = 0.f; ap[i] = 1.f; }

    size_t base = ((size_t)b * L_ + l0) * DM + dm;
    #pragma unroll 4
    for (int j = 0; j < CL; j++) {
        float dl  = (float)delta[base + (size_t)j * DM];
        float xv  = (float)xc[base + (size_t)j * DM];
        float cmn = dl * xv;
        const f32x4* sB4 = (const f32x4*)(sB + j * DS);
        #pragma unroll
        for (int r4 = 0; r4 < 4; r4++) {
            f32x4 bv = sB4[r4];
            #pragma unroll
            for (int q = 0; q < 4; q++) {
                int i = r4 * 4 + q;
                float dA = __expf(dl * Aval[i]);
                ap[i] *= dA;
                h[i] = fmaf(dA, h[i], cmn * bv[q]);
            }
        }
    }

    size_t s = ((size_t)(b * DM + dm)) * DS;
    #pragma unroll
    for (int r8 = 0; r8 < 2; r8++) {
        bf16x8 va, vh;
        #pragma unroll
        for (int q = 0; q < 8; q++) { va[q] = (__bf16)ap[r8 * 8 + q]; vh[q] = (__bf16)h[r8 * 8 + q]; }
        ((bf16x8*)(aprodB + (size_t)c * S_ + s))[r8] = va;
        ((bf16x8*)(cendB  + (size_t)c * S_ + s))[r8] = vh;
    }
}

// ---------------------------------------------------------------------------
// Chunked scan, phase 2: scan chunk summaries (bf16 in/out, f32 math).
// ---------------------------------------------------------------------------
__global__ void scan_phase2(const __bf16* __restrict__ aprodB, const __bf16* __restrict__ cendB,
                            __bf16* __restrict__ hinitB) {
    int u8 = (blockIdx.x * 256 + threadIdx.x) * 8;   // 0..S_-8
    float h[8];
    #pragma unroll
    for (int q = 0; q < 8; q++) h[q] = 0.f;
    #pragma unroll
    for (int c = 0; c < NC; c++) {
        bf16x8 a  = *(const bf16x8*)(aprodB + (size_t)c * S_ + u8);
        bf16x8 ce = *(const bf16x8*)(cendB  + (size_t)c * S_ + u8);
        bf16x8 ho;
        #pragma unroll
        for (int q = 0; q < 8; q++) {
            ho[q] = (__bf16)h[q];
            h[q] = fmaf((float)a[q], h[q], (float)ce[q]);
        }
        *(bf16x8*)(hinitB + (size_t)c * S_ + u8) = ho;
    }
}

// ---------------------------------------------------------------------------
// Chunked scan, phase 3: replay from h_init, fused epilogue -> bf16.
// Dense coalesced Bp/Cp.
// ---------------------------------------------------------------------------
__global__ void scan_phase3(const __bf16* __restrict__ delta, const __bf16* __restrict__ xc,
                            const float* __restrict__ Bp, const float* __restrict__ Cp,
                            const __bf16* __restrict__ res, const float* __restrict__ A_log,
                            const float* __restrict__ Dw, const __bf16* __restrict__ hinitB,
                            __bf16* __restrict__ ybar) {
    int blk = blockIdx.x;
    int c   = blk % NC;
    int rem = blk / NC;
    int dmt = rem % (DM / 256);
    int b   = rem / (DM / 256);
    int t   = threadIdx.x;
    int dm  = dmt * 256 + t;
    int l0  = c * CL;

    __shared__ float sB[CL * DS];      // 2 KB
    __shared__ float sC[CL * DS];      // 2 KB
    sB[t]       = Bp[((size_t)b * L_ + l0) * DS + t];
    sB[t + 256] = Bp[((size_t)b * L_ + l0) * DS + t + 256];
    sC[t]       = Cp[((size_t)b * L_ + l0) * DS + t];
    sC[t + 256] = Cp[((size_t)b * L_ + l0) * DS + t + 256];
    __syncthreads();

    float Aval[DS];
    {
        const f32x4* Ap = (const f32x4*)(A_log + (size_t)dm * DS);
        #pragma unroll
        for (int r4 = 0; r4 < 4; r4++) {
            f32x4 a = Ap[r4];
            #pragma unroll
            for (int q = 0; q < 4; q++) Aval[r4 * 4 + q] = -__expf(a[q]);
        }
    }
    float Dval = Dw[dm];

    float h[DS];
    {
        size_t s = ((size_t)(b * DM + dm)) * DS;
        #pragma unroll
        for (int r8 = 0; r8 < 2; r8++) {
            bf16x8 v = ((const bf16x8*)(hinitB + (size_t)c * S_ + s))[r8];
            #pragma unroll
            for (int q = 0; q < 8; q++) h[r8 * 8 + q] = (float)v[q];
        }
    }

    size_t base = ((size_t)b * L_ + l0) * DM + dm;
    #pragma unroll 4
    for (int j = 0; j < CL; j++) {
        float dl  = (float)delta[base + (size_t)j * DM];
        float xv  = (float)xc[base + (size_t)j * DM];
        float rv  = (float)res[base + (size_t)j * DM];
        float cmn = dl * xv;
        float y = 0.f;
        const f32x4* sB4 = (const f32x4*)(sB + j * DS);
        const f32x4* sC4 = (const f32x4*)(sC + j * DS);
        #pragma unroll
        for (int r4 = 0; r4 < 4; r4++) {
            f32x4 bv = sB4[r4];
            f32x4 cv = sC4[r4];
            #pragma unroll
            for (int q = 0; q < 4; q++) {
                int i = r4 * 4 + q;
                float dA = __expf(dl * Aval[i]);
                h[i] = fmaf(dA, h[i], cmn * bv[q]);
                y = fmaf(h[i], cv[q], y);
            }
        }
        float g = rv / (1.f + __expf(-rv));
        ybar[base + (size_t)j * DM] = (__bf16)((y + Dval * xv) * g);
    }
}

// ---------------------------------------------------------------------------
extern "C" void kernel_launch(void* const* d_in, const int* in_sizes, int n_in,
                              void* d_out, int out_size, void* d_ws, size_t ws_size,
                              hipStream_t stream) {
    // All reference tensors are float32.
    const float* x_in   = (const float*)d_in[0];
    const float* W_in   = (const float*)d_in[1];
    const float* W_res  = (const float*)d_in[2];
    const float* W_out  = (const float*)d_in[3];
    const float* conv_w = (const float*)d_in[4];
    const float* conv_b = (const float*)d_in[5];
    const float* A_log  = (const float*)d_in[6];
    const float* Dw     = (const float*)d_in[7];
    const float* W_B    = (const float*)d_in[8];
    const float* W_C    = (const float*)d_in[9];
    const float* W_dt   = (const float*)d_in[10];
    const float* dt_w   = (const float*)d_in[11];
    const float* dt_b   = (const float*)d_in[12];

    // ---------------- Workspace layout ----------------
    float* ws_f = (float*)d_ws;
    float* Bp    = ws_f;                        // M_*DS f32
    float* Cp    = Bp + (size_t)M_ * DS;        // M_*DS f32
    float* cwT   = Cp + (size_t)M_ * DS;        // KC*DM f32
    __bf16* bf_base = (__bf16*)(cwT + (size_t)KC * DM);
    __bf16* ybar   = bf_base;                   // M_*DM
    __bf16* xinB   = ybar   + (size_t)M_ * DM;  // M_*DIN
    __bf16* WinT   = xinB   + (size_t)M_ * DIN; // DM*DIN } adjacent: fused (4096 x DIN) BT
    __bf16* WresT  = WinT   + (size_t)DM * DIN; // DM*DIN }
    __bf16* WoutT  = WresT  + (size_t)DM * DIN; // DIN*DM
    __bf16* xB     = WoutT  + (size_t)DIN * DM; // M_*DM (conv input, bf16)
    __bf16* xcB    = xB     + (size_t)M_ * DM;  // M_*DM
    __bf16* projW  = xcB    + (size_t)M_ * DM;  // NP2*DM
    __bf16* dtwT   = projW  + (size_t)NP2 * DM; // DM*DR
    __bf16* dtmpB  = dtwT   + (size_t)DM * DR;  // M_*DR
    __bf16* deltaB = dtmpB  + (size_t)M_ * DR;  // M_*DM
    __bf16* resB   = deltaB + (size_t)M_ * DM;  // M_*DM
    __bf16* aprodB = resB   + (size_t)M_ * DM;  // NC*S_
    __bf16* cendB  = aprodB + (size_t)NC * S_;  // NC*S_
    __bf16* hinitB = cendB  + (size_t)NC * S_;  // NC*S_
    __bf16* PpartB = hinitB + (size_t)NC * S_;  // KSLICES*M_*NPC (compact bf16 partials)

    // ---------------- fused operand prep (1 launch) ----------------
    prep_all<<<16672, 256, 0, stream>>>(x_in, W_in, W_res, W_out, dt_w, W_B, W_C, W_dt,
                                        conv_w, xinB, WinT, WresT, WoutT, dtwT, projW, cwT);

    // Fused input GEMMs: [x (bf16) | res (bf16)] = x_in @ [W_in | W_res]
    gemm_tile128<2><<<dim3((2 * DM) / 128, M_ / 128, 1), 256, 0, stream>>>(
        xinB, WinT, (float*)xB, resB, nullptr, M_, 2 * DM, DIN, DIN, DIN);

    conv_silu<<<M_, 256, 0, stream>>>(xB, cwT, conv_b, xcB);

    // Packed projections, split-K -> compact bf16 partials (stride NPC)
    gemm_tile128<4><<<dim3(NP2 / 128, M_ / 128, KSLICES), 256, 0, stream>>>(
        xcB, projW, nullptr, PpartB, nullptr, M_, NP2, KSL, DM, DM);
    reduce_split<<<(M_ * NPC) / 256, 256, 0, stream>>>(PpartB, Bp, Cp, dtmpB);

    // delta = softplus(dtmp @ dt_w + dt_b) -> bf16  (M_ x DM, K=DR)
    gemm_tile128<1><<<dim3(DM / 128, M_ / 128, 1), 256, 0, stream>>>(
        dtmpB, dtwT, nullptr, deltaB, dt_b, M_, DM, DR, DR, DR);

    // Chunked selective scan (3 launches; kernel boundary = cheap barrier)
    int nblk = B_ * (DM / 256) * NC;   // 512
    scan_phase1<<<nblk, 256, 0, stream>>>(deltaB, xcB, Bp, A_log, aprodB, cendB);
    scan_phase2<<<S_ / (256 * 8), 256, 0, stream>>>(aprodB, cendB, hinitB);
    scan_phase3<<<nblk, 256, 0, stream>>>(deltaB, xcB, Bp, Cp, resB, A_log, Dw, hinitB, ybar);

    // out = ybar @ W_out  (M_ x DIN, K=DM), direct f32 store, 256 blocks
    gemm_out64<<<dim3(DIN / 64, M_ / 128), 256, 0, stream>>>(
        ybar, WoutT, (float*)d_out, M_, DIN, DM, DM, DM);
}